// Round 9
// baseline (154.872 us; speedup 1.0000x reference)
//
#include <hip/hip_runtime.h>

#define EDGE_BLOCKS  768
#define EDGE_THREADS 512
#define PACK_WORDS_MAX 12512   // 50,048 B LDS table -> supports n_nodes <= 100,096

// ws layout (bytes):
//   [8192, 8192+4*n_words) : packed 4-bit node-class table
#define WS_PACK_OFF    8192

#define LOG2E 1.44269504088896f
#define LN2   0.69314718055995f

// Persistent device-global accumulator (graph-replay safe: last block resets).
__device__ double       g_acc = 0.0;
__device__ unsigned int g_cnt = 0u;

// ---------- kernel A: pack node classes to nibbles (once, 400KB -> 50KB) ----------
__global__ __launch_bounds__(256) void pack_classes(
    const int* __restrict__ node_classes,
    unsigned* __restrict__ packed,
    int n_nodes, int n_words)
{
    int w = blockIdx.x * blockDim.x + threadIdx.x;
    if (w >= n_words) return;

    int base = w << 3;
    unsigned v = 0;
    if (base + 8 <= n_nodes) {
        const int4* p = (const int4*)(node_classes + base);
        int4 c0 = p[0];
        int4 c1 = p[1];
        v  = ((unsigned)c0.x & 0xFu)
           | (((unsigned)c0.y & 0xFu) << 4)
           | (((unsigned)c0.z & 0xFu) << 8)
           | (((unsigned)c0.w & 0xFu) << 12)
           | (((unsigned)c1.x & 0xFu) << 16)
           | (((unsigned)c1.y & 0xFu) << 20)
           | (((unsigned)c1.z & 0xFu) << 24)
           | (((unsigned)c1.w & 0xFu) << 28);
    } else {
        #pragma unroll
        for (int j = 0; j < 8; ++j) {
            int n = base + j;
            unsigned c = (n < n_nodes) ? (unsigned)node_classes[n] : 0u;
            v |= (c & 0xFu) << (4 * j);
        }
    }
    packed[w] = v;
}

// ---------- kernel B: edge loss — EXACT round-1 champion structure ----------
// 768 blocks x 512 threads, launch_bounds(512,6): 3 blocks/CU (LDS 3x50KB =
// 150KB <= 160KB), 24 waves/CU, 84-VGPR cap. This config ran <42us (r1 total
// 122.3us, prior-session 120.5us) and beat every 1024-thread/64-VGPR variant
// (46us). Hypothesis: the 84-reg headroom lets the depth-1 pipeline's ~36
// payload regs survive regalloc; VGPR_Count this round is the diagnostic.
// Only delta vs r1: atomic finish replaces partial[]+final_reduce launch.
__global__ __launch_bounds__(EDGE_THREADS, 6) void edge_loss_lds(
    const unsigned* __restrict__ packed_g,
    const float* __restrict__ edge_scores,
    const int*   __restrict__ edge_src,
    const int*   __restrict__ edge_dst,
    const float* __restrict__ adj,
    float*       __restrict__ out,
    int n_edges, int n_words, float inv_n)
{
    __shared__ unsigned s_packed[PACK_WORDS_MAX]; // 50,048 B
    __shared__ unsigned s_mask[16];
    __shared__ float    s_wsum[EDGE_THREADS / 64];

    const int tid = threadIdx.x;

    if (tid < 16) {
        unsigned m = 0u;
        if (tid < 12) {
            #pragma unroll
            for (int j = 0; j < 12; ++j)
                if (adj[tid * 12 + j] > 0.5f) m |= (1u << j);
        }
        s_mask[tid] = m;
    }
    {
        int nv = n_words >> 2;
        const uint4* p4 = (const uint4*)packed_g;
        for (int i = tid; i < nv; i += EDGE_THREADS) {
            uint4 v = p4[i];
            s_packed[4*i+0] = v.x; s_packed[4*i+1] = v.y;
            s_packed[4*i+2] = v.z; s_packed[4*i+3] = v.w;
        }
        for (int i = (nv << 2) + tid; i < n_words; i += EDGE_THREADS)
            s_packed[i] = packed_g[i];
    }
    __syncthreads();

    const int gtid   = blockIdx.x * EDGE_THREADS + tid;
    const int stride = gridDim.x * EDGE_THREADS;
    const int ngrp   = n_edges >> 2;

    const int4*   srcv = (const int4*)  edge_src;
    const int4*   dstv = (const int4*)  edge_dst;
    const float4* scov = (const float4*)edge_scores;

    float acc_a = 0.0f;   // max(s,0) - y*s terms
    float acc_l = 0.0f;   // log-domain softplus terms (scale by LN2 at end)

    int g = gtid;
    if (g < ngrp) {
        // --- software pipeline: prefetch trip 0 ---
        int4   si = srcv[g];
        int4   di = dstv[g];
        float4 sc = scov[g];

        while (true) {
            const int gn = g + stride;
            int4 si_n, di_n; float4 sc_n;
            const bool more = (gn < ngrp);
            if (more) {              // issue next trip's loads before compute
                si_n = srcv[gn];
                di_n = dstv[gn];
                sc_n = scov[gn];
            }

            // nibble gathers (random LDS)
            unsigned wa0 = s_packed[si.x >> 3], wa1 = s_packed[si.y >> 3];
            unsigned wa2 = s_packed[si.z >> 3], wa3 = s_packed[si.w >> 3];
            unsigned wb0 = s_packed[di.x >> 3], wb1 = s_packed[di.y >> 3];
            unsigned wb2 = s_packed[di.z >> 3], wb3 = s_packed[di.w >> 3];

            int a0 = (wa0 >> ((si.x & 7) << 2)) & 0xF;
            int a1 = (wa1 >> ((si.y & 7) << 2)) & 0xF;
            int a2 = (wa2 >> ((si.z & 7) << 2)) & 0xF;
            int a3 = (wa3 >> ((si.w & 7) << 2)) & 0xF;
            int b0 = (wb0 >> ((di.x & 7) << 2)) & 0xF;
            int b1 = (wb1 >> ((di.y & 7) << 2)) & 0xF;
            int b2 = (wb2 >> ((di.z & 7) << 2)) & 0xF;
            int b3 = (wb3 >> ((di.w & 7) << 2)) & 0xF;

            unsigned y0 = (s_mask[a0] >> b0) & 1u;
            unsigned y1 = (s_mask[a1] >> b1) & 1u;
            unsigned y2 = (s_mask[a2] >> b2) & 1u;
            unsigned y3 = (s_mask[a3] >> b3) & 1u;

            float s0 = sc.x, s1 = sc.y, s2 = sc.z, s3 = sc.w;

            float t0 = __builtin_amdgcn_exp2f(-fabsf(s0) * LOG2E);
            float t1 = __builtin_amdgcn_exp2f(-fabsf(s1) * LOG2E);
            float t2 = __builtin_amdgcn_exp2f(-fabsf(s2) * LOG2E);
            float t3 = __builtin_amdgcn_exp2f(-fabsf(s3) * LOG2E);

            acc_a += fmaxf(s0, 0.0f) - (y0 ? s0 : 0.0f);
            acc_a += fmaxf(s1, 0.0f) - (y1 ? s1 : 0.0f);
            acc_a += fmaxf(s2, 0.0f) - (y2 ? s2 : 0.0f);
            acc_a += fmaxf(s3, 0.0f) - (y3 ? s3 : 0.0f);

            acc_l += __builtin_amdgcn_logf(1.0f + t0);
            acc_l += __builtin_amdgcn_logf(1.0f + t1);
            acc_l += __builtin_amdgcn_logf(1.0f + t2);
            acc_l += __builtin_amdgcn_logf(1.0f + t3);

            if (!more) break;
            si = si_n; di = di_n; sc = sc_n; g = gn;
        }
    }

    // scalar tail (n_edges not divisible by 4)
    for (int e = (ngrp << 2) + gtid; e < n_edges; e += stride) {
        int n = edge_src[e], m = edge_dst[e];
        int a = (s_packed[n >> 3] >> ((n & 7) << 2)) & 0xF;
        int b = (s_packed[m >> 3] >> ((m & 7) << 2)) & 0xF;
        unsigned y = (s_mask[a] >> b) & 1u;
        float s = edge_scores[e];
        float t = __builtin_amdgcn_exp2f(-fabsf(s) * LOG2E);
        acc_a += fmaxf(s, 0.0f) - (y ? s : 0.0f);
        acc_l += __builtin_amdgcn_logf(1.0f + t);
    }

    float acc = fmaf(LN2, acc_l, acc_a);

    #pragma unroll
    for (int off = 32; off > 0; off >>= 1)
        acc += __shfl_down(acc, off, 64);

    const int wave = tid >> 6;
    const int lane = tid & 63;
    if (lane == 0) s_wsum[wave] = acc;
    __syncthreads();

    if (tid == 0) {
        double bsum = 0.0;
        #pragma unroll
        for (int w = 0; w < EDGE_THREADS / 64; ++w) bsum += (double)s_wsum[w];

        atomicAdd(&g_acc, bsum);
        __threadfence();
        unsigned old = atomicAdd(&g_cnt, 1u);
        if (old == gridDim.x - 1) {
            __threadfence();
            double total = g_acc;
            out[0] = (float)(total * (double)inv_n);
            g_acc = 0.0;          // restore clean state for next graph replay
            __threadfence();
            g_cnt = 0u;
        }
    }
}

// ---------- fallback: too many nodes for the LDS table ----------
__global__ __launch_bounds__(256) void edge_loss_fallback(
    const int*   __restrict__ node_classes,
    const float* __restrict__ edge_scores,
    const int*   __restrict__ edge_src,
    const int*   __restrict__ edge_dst,
    const float* __restrict__ adj,
    float*       __restrict__ out,
    int n_edges, float inv_n)
{
    __shared__ unsigned s_mask[16];
    const int tid = threadIdx.x;
    if (tid < 12) {
        unsigned m = 0u;
        for (int j = 0; j < 12; ++j)
            if (adj[tid * 12 + j] > 0.5f) m |= (1u << j);
        s_mask[tid] = m;
    }
    __syncthreads();
    const int gtid   = blockIdx.x * 256 + tid;
    const int stride = gridDim.x * 256;
    float acc = 0.0f;
    for (int e = gtid; e < n_edges; e += stride) {
        int a = node_classes[edge_src[e]];
        int b = node_classes[edge_dst[e]];
        float y = (float)((s_mask[a] >> b) & 1u);
        float s = edge_scores[e];
        float t = __builtin_amdgcn_exp2f(-fabsf(s) * LOG2E);
        acc += fmaxf(s, 0.0f) - s * y + LN2 * __builtin_amdgcn_logf(1.0f + t);
    }
    #pragma unroll
    for (int off = 32; off > 0; off >>= 1)
        acc += __shfl_down(acc, off, 64);
    __shared__ float s_wsum[4];
    const int wave = tid >> 6, lane = tid & 63;
    if (lane == 0) s_wsum[wave] = acc;
    __syncthreads();
    if (tid == 0) {
        double bsum = (double)s_wsum[0] + (double)s_wsum[1]
                    + (double)s_wsum[2] + (double)s_wsum[3];
        atomicAdd(&g_acc, bsum);
        __threadfence();
        unsigned old = atomicAdd(&g_cnt, 1u);
        if (old == gridDim.x - 1) {
            __threadfence();
            double total = g_acc;
            out[0] = (float)(total * (double)inv_n);
            g_acc = 0.0;
            __threadfence();
            g_cnt = 0u;
        }
    }
}

extern "C" void kernel_launch(void* const* d_in, const int* in_sizes, int n_in,
                              void* d_out, int out_size, void* d_ws, size_t ws_size,
                              hipStream_t stream) {
    const int*   node_classes = (const int*)  d_in[0];
    const float* edge_scores  = (const float*)d_in[1];
    const int*   edge_indices = (const int*)  d_in[2];
    const float* adj          = (const float*)d_in[3];

    const int n_nodes = in_sizes[0];
    const int n_edges = in_sizes[1];
    const int n_words = (n_nodes + 7) >> 3;

    const int* edge_src = edge_indices;
    const int* edge_dst = edge_indices + n_edges;

    char* ws = (char*)d_ws;
    unsigned* packed = (unsigned*)(ws + WS_PACK_OFF);
    float* out = (float*)d_out;
    const float inv_n = 1.0f / (float)n_edges;

    const size_t needed = (size_t)WS_PACK_OFF + (size_t)n_words * 4u;

    if (ws_size >= needed && n_words <= PACK_WORDS_MAX) {
        int pack_blocks = (n_words + 255) / 256;
        pack_classes<<<pack_blocks, 256, 0, stream>>>(
            node_classes, packed, n_nodes, n_words);
        edge_loss_lds<<<EDGE_BLOCKS, EDGE_THREADS, 0, stream>>>(
            packed, edge_scores, edge_src, edge_dst, adj, out,
            n_edges, n_words, inv_n);
    } else {
        edge_loss_fallback<<<2048, 256, 0, stream>>>(
            node_classes, edge_scores, edge_src, edge_dst, adj, out,
            n_edges, inv_n);
    }
}

// Round 11
// 118.793 us; speedup vs baseline: 1.3037x; 1.3037x over previous
//
#include <hip/hip_runtime.h>

#define EDGE_BLOCKS  512
#define EDGE_THREADS 1024
#define PACK_WORDS_MAX 12512   // 50,048 B LDS table -> supports n_nodes <= 100,096

// ws layout (bytes):
//   [256, 256+max(EDGE_BLOCKS,2048)*4) : per-block float partials
//   [16384, 16384+4*n_words)           : packed 4-bit node-class table
#define WS_PART_OFF    256
#define WS_PACK_OFF    16384

#define LOG2E 1.44269504088896f
#define LN2   0.69314718055995f

typedef int   i32x4 __attribute__((ext_vector_type(4)));
typedef float f32x4 __attribute__((ext_vector_type(4)));

// ---------- kernel A: pack node classes to nibbles (once, 400KB -> 50KB) ----------
__global__ __launch_bounds__(256) void pack_classes(
    const int* __restrict__ node_classes,
    unsigned* __restrict__ packed,
    int n_nodes, int n_words)
{
    int w = blockIdx.x * blockDim.x + threadIdx.x;
    if (w >= n_words) return;

    int base = w << 3;
    unsigned v = 0;
    if (base + 8 <= n_nodes) {
        const int4* p = (const int4*)(node_classes + base);
        int4 c0 = p[0];
        int4 c1 = p[1];
        v  = ((unsigned)c0.x & 0xFu)
           | (((unsigned)c0.y & 0xFu) << 4)
           | (((unsigned)c0.z & 0xFu) << 8)
           | (((unsigned)c0.w & 0xFu) << 12)
           | (((unsigned)c1.x & 0xFu) << 16)
           | (((unsigned)c1.y & 0xFu) << 20)
           | (((unsigned)c1.z & 0xFu) << 24)
           | (((unsigned)c1.w & 0xFu) << 28);
    } else {
        #pragma unroll
        for (int j = 0; j < 8; ++j) {
            int n = base + j;
            unsigned c = (n < n_nodes) ? (unsigned)node_classes[n] : 0u;
            v |= (c & 0xFu) << (4 * j);
        }
    }
    packed[w] = v;
}

// Pinned 16B load (asm volatile: cannot be sunk or reordered vs other asm).
#define GLOAD4(dst, voff, sbase)                                              \
    asm volatile("global_load_dwordx4 %0, %1, %2"                             \
                 : "=v"(dst) : "v"(voff), "s"(sbase) : "memory")

// Counted wait + scheduler fence (rule #18).
#define WAITV(n)                                                              \
    do {                                                                      \
        asm volatile("s_waitcnt vmcnt(" #n ")" ::: "memory");                 \
        __builtin_amdgcn_sched_barrier(0);                                    \
    } while (0)

// 4-edge compute body: accumulates into the two named float accumulators.
#define COMPUTE4(si, di, sc, aa, al)                                          \
    do {                                                                      \
        unsigned wa0 = s_packed[(si).x >> 3], wa1 = s_packed[(si).y >> 3];    \
        unsigned wa2 = s_packed[(si).z >> 3], wa3 = s_packed[(si).w >> 3];    \
        unsigned wb0 = s_packed[(di).x >> 3], wb1 = s_packed[(di).y >> 3];    \
        unsigned wb2 = s_packed[(di).z >> 3], wb3 = s_packed[(di).w >> 3];    \
        int a0 = (wa0 >> (((si).x & 7) << 2)) & 0xF;                          \
        int a1 = (wa1 >> (((si).y & 7) << 2)) & 0xF;                          \
        int a2 = (wa2 >> (((si).z & 7) << 2)) & 0xF;                          \
        int a3 = (wa3 >> (((si).w & 7) << 2)) & 0xF;                          \
        int b0 = (wb0 >> (((di).x & 7) << 2)) & 0xF;                          \
        int b1 = (wb1 >> (((di).y & 7) << 2)) & 0xF;                          \
        int b2 = (wb2 >> (((di).z & 7) << 2)) & 0xF;                          \
        int b3 = (wb3 >> (((di).w & 7) << 2)) & 0xF;                          \
        unsigned y0 = (s_mask[a0] >> b0) & 1u;                                \
        unsigned y1 = (s_mask[a1] >> b1) & 1u;                                \
        unsigned y2 = (s_mask[a2] >> b2) & 1u;                                \
        unsigned y3 = (s_mask[a3] >> b3) & 1u;                                \
        float s0 = (sc).x, s1 = (sc).y, s2 = (sc).z, s3 = (sc).w;             \
        float t0 = __builtin_amdgcn_exp2f(-fabsf(s0) * LOG2E);                \
        float t1 = __builtin_amdgcn_exp2f(-fabsf(s1) * LOG2E);                \
        float t2 = __builtin_amdgcn_exp2f(-fabsf(s2) * LOG2E);                \
        float t3 = __builtin_amdgcn_exp2f(-fabsf(s3) * LOG2E);                \
        aa += fmaxf(s0, 0.0f) - (y0 ? s0 : 0.0f);                            \
        aa += fmaxf(s1, 0.0f) - (y1 ? s1 : 0.0f);                            \
        aa += fmaxf(s2, 0.0f) - (y2 ? s2 : 0.0f);                            \
        aa += fmaxf(s3, 0.0f) - (y3 ? s3 : 0.0f);                            \
        al += __builtin_amdgcn_logf(1.0f + t0);                               \
        al += __builtin_amdgcn_logf(1.0f + t1);                               \
        al += __builtin_amdgcn_logf(1.0f + t2);                               \
        al += __builtin_amdgcn_logf(1.0f + t3);                               \
    } while (0)

// ---------- kernel B: edge loss (r8 body, UNCHANGED) + partial[] finish ------
// 512 blocks x 1024 threads = 2 blocks/CU (LDS 2x50KB), 32 waves/CU.
// ONLY delta vs round 8: the single-address double-atomic finish (measured as
// a ~12-20us serialized cross-XCD tail: r1<42 vs r9=61 at identical body) is
// replaced by per-block partial[] write + final_reduce (Guideline 12).
__global__ __launch_bounds__(EDGE_THREADS, 8) void edge_loss_lds(
    const unsigned* __restrict__ packed_g,
    const float* __restrict__ edge_scores,
    const int*   __restrict__ edge_src,
    const int*   __restrict__ edge_dst,
    const float* __restrict__ adj,
    float*       __restrict__ partial,
    int n_edges, int n_words)
{
    __shared__ unsigned s_packed[PACK_WORDS_MAX]; // 50,048 B
    __shared__ unsigned s_mask[16];
    __shared__ float    s_wsum[EDGE_THREADS / 64];

    const int tid  = threadIdx.x;
    const int gtid = blockIdx.x * EDGE_THREADS + tid;
    const int S    = gridDim.x * EDGE_THREADS;   // 524,288 threads
    const int noct = n_edges >> 2;               // 4-edge groups

    if (tid < 16) {
        unsigned m = 0u;
        if (tid < 12) {
            #pragma unroll
            for (int j = 0; j < 12; ++j)
                if (adj[tid * 12 + j] > 0.5f) m |= (1u << j);
        }
        s_mask[tid] = m;
    }
    {
        // stage the 50KB packed table (L2-resident: 512 blocks x 50KB = 25MB)
        int nv = n_words >> 2;
        const uint4* p4 = (const uint4*)packed_g;
        for (int i = tid; i < nv; i += EDGE_THREADS) {
            uint4 v = p4[i];
            s_packed[4*i+0] = v.x; s_packed[4*i+1] = v.y;
            s_packed[4*i+2] = v.z; s_packed[4*i+3] = v.w;
        }
        for (int i = (nv << 2) + tid; i < n_words; i += EDGE_THREADS)
            s_packed[i] = packed_g[i];
    }
    __syncthreads();   // compiler emits s_waitcnt vmcnt(0) before s_barrier

    float acc_a = 0.0f;   // max(s,0) - y*s terms
    float acc_l = 0.0f;   // log-domain softplus terms (scale by LN2 at end)

    if (noct > 0) {   // uniform branch
        const int  g0 = gtid;
        const bool mA = (g0 < noct);
        const bool mB = (g0 +     S) < noct;
        const bool mC = (g0 + 2 * S) < noct;
        const bool mD = (g0 + 3 * S) < noct;
        const int  cA = mA ? g0           : 0;
        const int  cB = mB ? (g0 + S)     : cA;
        const int  cC = mC ? (g0 + 2 * S) : cA;
        const int  cD = mD ? (g0 + 3 * S) : cA;
        const unsigned oA = (unsigned)cA << 4;   // 16B per group in all 3 streams
        const unsigned oB = (unsigned)cB << 4;
        const unsigned oC = (unsigned)cC << 4;
        const unsigned oD = (unsigned)cD << 4;

        i32x4 siA, diA, siB, diB, siC, diC, siD, diD;
        f32x4 scA, scB, scC, scD;
        float aT, lT;

        // issue A,B (6 loads in flight)
        GLOAD4(siA, oA, edge_src); GLOAD4(diA, oA, edge_dst); GLOAD4(scA, oA, edge_scores);
        GLOAD4(siB, oB, edge_src); GLOAD4(diB, oB, edge_dst); GLOAD4(scB, oB, edge_scores);

        WAITV(3);                                  // A complete, B in flight
        aT = 0.0f; lT = 0.0f;
        COMPUTE4(siA, diA, scA, aT, lT);
        acc_a += mA ? aT : 0.0f;  acc_l += mA ? lT : 0.0f;

        GLOAD4(siC, oC, edge_src); GLOAD4(diC, oC, edge_dst); GLOAD4(scC, oC, edge_scores);

        WAITV(3);                                  // B complete, C in flight
        aT = 0.0f; lT = 0.0f;
        COMPUTE4(siB, diB, scB, aT, lT);
        acc_a += mB ? aT : 0.0f;  acc_l += mB ? lT : 0.0f;

        GLOAD4(siD, oD, edge_src); GLOAD4(diD, oD, edge_dst); GLOAD4(scD, oD, edge_scores);

        WAITV(3);                                  // C complete, D in flight
        aT = 0.0f; lT = 0.0f;
        COMPUTE4(siC, diC, scC, aT, lT);
        acc_a += mC ? aT : 0.0f;  acc_l += mC ? lT : 0.0f;

        WAITV(0);                                  // D complete
        aT = 0.0f; lT = 0.0f;
        COMPUTE4(siD, diD, scD, aT, lT);
        acc_a += mD ? aT : 0.0f;  acc_l += mD ? lT : 0.0f;
    }

    // generality: groups beyond 4 per thread (empty at this problem size)
    {
        const int4*   srcv = (const int4*)  edge_src;
        const int4*   dstv = (const int4*)  edge_dst;
        const float4* scov = (const float4*)edge_scores;
        for (int g = gtid + 4 * S; g < noct; g += S) {
            int4 si = srcv[g], di = dstv[g]; float4 sc = scov[g];
            COMPUTE4(si, di, sc, acc_a, acc_l);
        }
    }

    // scalar tail (n_edges not divisible by 4)
    for (int e = (noct << 2) + gtid; e < n_edges; e += S) {
        int n = edge_src[e], m = edge_dst[e];
        int a = (s_packed[n >> 3] >> ((n & 7) << 2)) & 0xF;
        int b = (s_packed[m >> 3] >> ((m & 7) << 2)) & 0xF;
        unsigned y = (s_mask[a] >> b) & 1u;
        float s = edge_scores[e];
        float t = __builtin_amdgcn_exp2f(-fabsf(s) * LOG2E);
        acc_a += fmaxf(s, 0.0f) - (y ? s : 0.0f);
        acc_l += __builtin_amdgcn_logf(1.0f + t);
    }

    float acc = fmaf(LN2, acc_l, acc_a);

    #pragma unroll
    for (int off = 32; off > 0; off >>= 1)
        acc += __shfl_down(acc, off, 64);

    const int wave = tid >> 6;
    const int lane = tid & 63;
    if (lane == 0) s_wsum[wave] = acc;
    __syncthreads();

    if (tid == 0) {
        float b = 0.0f;
        #pragma unroll
        for (int w = 0; w < EDGE_THREADS / 64; ++w) b += s_wsum[w];
        partial[blockIdx.x] = b;          // one store per block; no global RMW
    }
}

// ---------- fallback: too many nodes for the LDS table ----------
__global__ __launch_bounds__(256) void edge_loss_fallback(
    const int*   __restrict__ node_classes,
    const float* __restrict__ edge_scores,
    const int*   __restrict__ edge_src,
    const int*   __restrict__ edge_dst,
    const float* __restrict__ adj,
    float*       __restrict__ partial,
    int n_edges)
{
    __shared__ unsigned s_mask[16];
    const int tid = threadIdx.x;
    if (tid < 12) {
        unsigned m = 0u;
        for (int j = 0; j < 12; ++j)
            if (adj[tid * 12 + j] > 0.5f) m |= (1u << j);
        s_mask[tid] = m;
    }
    __syncthreads();
    const int gtid   = blockIdx.x * 256 + tid;
    const int stride = gridDim.x * 256;
    float acc = 0.0f;
    for (int e = gtid; e < n_edges; e += stride) {
        int a = node_classes[edge_src[e]];
        int b = node_classes[edge_dst[e]];
        float y = (float)((s_mask[a] >> b) & 1u);
        float s = edge_scores[e];
        float t = __builtin_amdgcn_exp2f(-fabsf(s) * LOG2E);
        acc += fmaxf(s, 0.0f) - s * y + LN2 * __builtin_amdgcn_logf(1.0f + t);
    }
    #pragma unroll
    for (int off = 32; off > 0; off >>= 1)
        acc += __shfl_down(acc, off, 64);
    __shared__ float s_wsum[4];
    const int wave = tid >> 6, lane = tid & 63;
    if (lane == 0) s_wsum[wave] = acc;
    __syncthreads();
    if (tid == 0) {
        float b = 0.0f;
        for (int w = 0; w < 4; ++w) b += s_wsum[w];
        partial[blockIdx.x] = b;
    }
}

__global__ __launch_bounds__(256) void final_reduce(
    const float* __restrict__ partial,
    float*       __restrict__ out,
    int nblk, float inv_n)
{
    const int tid = threadIdx.x;
    double acc = 0.0;
    for (int i = tid; i < nblk; i += 256) acc += (double)partial[i];
    #pragma unroll
    for (int off = 32; off > 0; off >>= 1)
        acc += __shfl_down(acc, off, 64);
    __shared__ double s_wsum[4];
    const int wave = tid >> 6, lane = tid & 63;
    if (lane == 0) s_wsum[wave] = acc;
    __syncthreads();
    if (tid == 0) {
        double t = s_wsum[0] + s_wsum[1] + s_wsum[2] + s_wsum[3];
        out[0] = (float)(t * (double)inv_n);
    }
}

extern "C" void kernel_launch(void* const* d_in, const int* in_sizes, int n_in,
                              void* d_out, int out_size, void* d_ws, size_t ws_size,
                              hipStream_t stream) {
    const int*   node_classes = (const int*)  d_in[0];
    const float* edge_scores  = (const float*)d_in[1];
    const int*   edge_indices = (const int*)  d_in[2];
    const float* adj          = (const float*)d_in[3];

    const int n_nodes = in_sizes[0];
    const int n_edges = in_sizes[1];
    const int n_words = (n_nodes + 7) >> 3;

    const int* edge_src = edge_indices;
    const int* edge_dst = edge_indices + n_edges;

    char* ws = (char*)d_ws;
    float*    partial = (float*)   (ws + WS_PART_OFF);
    unsigned* packed  = (unsigned*)(ws + WS_PACK_OFF);
    float* out = (float*)d_out;
    const float inv_n = 1.0f / (float)n_edges;

    const size_t needed = (size_t)WS_PACK_OFF + (size_t)n_words * 4u;

    if (ws_size >= needed && n_words <= PACK_WORDS_MAX) {
        int pack_blocks = (n_words + 255) / 256;
        pack_classes<<<pack_blocks, 256, 0, stream>>>(
            node_classes, packed, n_nodes, n_words);
        edge_loss_lds<<<EDGE_BLOCKS, EDGE_THREADS, 0, stream>>>(
            packed, edge_scores, edge_src, edge_dst, adj, partial,
            n_edges, n_words);
        final_reduce<<<1, 256, 0, stream>>>(partial, out, EDGE_BLOCKS, inv_n);
    } else {
        edge_loss_fallback<<<2048, 256, 0, stream>>>(
            node_classes, edge_scores, edge_src, edge_dst, adj, partial, n_edges);
        final_reduce<<<1, 256, 0, stream>>>(partial, out, 2048, inv_n);
    }
}